// Round 4
// baseline (303.983 us; speedup 1.0000x reference)
//
#include <hip/hip_runtime.h>
#include <hip/hip_bf16.h>
#include <stdint.h>

#define TT   65536
#define NCH  16
#define CNOM 16
#define NBLK 256
#define ROWB 1664            // bytes per packed igate row (6*256 used + 128 pad)

typedef __bf16 bf16x8 __attribute__((ext_vector_type(8)));
typedef float  f32x4  __attribute__((ext_vector_type(4)));
typedef int    i32x4  __attribute__((ext_vector_type(4)));

__device__ __bf16 g_wih[768 * 256];
__device__ __bf16 g_whh[768 * 256];
__device__ __align__(64) unsigned char g_ig[(size_t)TT * ROWB];

__device__ __forceinline__ void gl_lds16(const void* g, void* l) {
  __builtin_amdgcn_global_load_lds(
      (const __attribute__((address_space(1))) void*)(unsigned long long)(uintptr_t)g,
      (__attribute__((address_space(3))) void*)(unsigned int)(uintptr_t)l,
      16, 0, 0);
}

__device__ __forceinline__ float bfbits(uint32_t u) {
  float f; __builtin_memcpy(&f, &u, 4); return f;
}

// asm MFMA wrappers. *_0 variants use inline-constant 0 as srcC (no VALU init,
// no VALU->MFMA srcC hazard); "=&v" early-clobber so dst never aliases srcA/B.
// Accumulate variants tie dst to srcC ("+v") -> alias-safe by construction.
// B register class is explicit: "v" (LDS-loaded r-gate) or "a" (AGPR-pinned
// z/n gates -> zero accvgpr shuttling per use).
__device__ __forceinline__ void mfma_bv0(f32x4& acc, bf16x8 a, i32x4 b) {
  asm("v_mfma_f32_16x16x32_bf16 %0, %1, %2, 0" : "=&v"(acc) : "v"(a), "v"(b));
}
__device__ __forceinline__ void mfma_ba0(f32x4& acc, bf16x8 a, i32x4 b) {
  asm("v_mfma_f32_16x16x32_bf16 %0, %1, %2, 0" : "=&v"(acc) : "v"(a), "a"(b));
}
__device__ __forceinline__ void mfma_bv(f32x4& acc, bf16x8 a, i32x4 b) {
  asm("v_mfma_f32_16x16x32_bf16 %0, %1, %2, %0" : "+v"(acc) : "v"(a), "v"(b));
}
__device__ __forceinline__ void mfma_ba(f32x4& acc, bf16x8 a, i32x4 b) {
  asm("v_mfma_f32_16x16x32_bf16 %0, %1, %2, %0" : "+v"(acc) : "v"(a), "a"(b));
}

__global__ void prep_w(const float* __restrict__ wih, const float* __restrict__ whh) {
  const int n = 768 * 256;
  for (int i = blockIdx.x * blockDim.x + threadIdx.x; i < n; i += gridDim.x * blockDim.x) {
    g_wih[i] = (__bf16)wih[i];
    g_whh[i] = (__bf16)whh[i];
  }
}

// phase 1: igates = x @ W_ih^T + bias -> packed rows, fully coalesced writes.
// A path: reg-staged f32 x with inline f32->bf16 convert (prep_x deleted).
// Swizzle on the LDS-write side: thread for (row, slot c) loads global chunk
// c^(row&7), writes LDS slot c; read side reads slot (ks*4+q)^(row&7) ->
// retrieves linear chunk ks*4+q. Identical layout to the old global-side swz.
__global__ __launch_bounds__(256) void gemm_ig(const float* __restrict__ x,
                                               const float* __restrict__ bias) {
  __shared__ __align__(16) __bf16 a_s[128 * 64];
  __shared__ __align__(16) __bf16 b_s[128 * 64];
  const int tid = threadIdx.x;
  const int w = tid >> 6, lane = tid & 63, l15 = lane & 15, q = lane >> 4;
  const int mt = blockIdx.x / 6, ntb = blockIdx.x - mt * 6;
  const int m0 = mt * 128, n0 = ntb * 128;
  const int wm = w >> 1, wn = w & 1;

  f32x4 acc[4][4];
#pragma unroll
  for (int a = 0; a < 4; ++a)
#pragma unroll
    for (int b = 0; b < 4; ++b) acc[a][b] = (f32x4){0.f, 0.f, 0.f, 0.f};

  for (int kc = 0; kc < 4; ++kc) {
#pragma unroll
    for (int i = 0; i < 4; ++i) {
      int pslot = i * 256 + tid;
      int row = pslot >> 3, c = pslot & 7;
      int cs = c ^ (row & 7);
      const float* xs = x + (size_t)(m0 + row) * 256 + kc * 64 + cs * 8;
      float4 f0 = *(const float4*)xs;
      float4 f1 = *(const float4*)(xs + 4);
      bf16x8 v;
      v[0] = (__bf16)f0.x; v[1] = (__bf16)f0.y; v[2] = (__bf16)f0.z; v[3] = (__bf16)f0.w;
      v[4] = (__bf16)f1.x; v[5] = (__bf16)f1.y; v[6] = (__bf16)f1.z; v[7] = (__bf16)f1.w;
      *(bf16x8*)((char*)a_s + pslot * 16) = v;
      gl_lds16((const char*)g_wih + ((size_t)(n0 + row) * 256 + kc * 64) * 2 + cs * 16,
               (char*)b_s + (i * 256 + (tid & ~63)) * 16);
    }
    __syncthreads();
#pragma unroll
    for (int ks = 0; ks < 2; ++ks) {
      bf16x8 af[4], bfr[4];
#pragma unroll
      for (int tm = 0; tm < 4; ++tm) {
        int row = wm * 64 + tm * 16 + l15;
        int cb = (ks * 4 + q) ^ (row & 7);
        af[tm] = *(const bf16x8*)((const char*)a_s + row * 128 + cb * 16);
      }
#pragma unroll
      for (int tn = 0; tn < 4; ++tn) {
        int row = wn * 64 + tn * 16 + l15;
        int cb = (ks * 4 + q) ^ (row & 7);
        bfr[tn] = *(const bf16x8*)((const char*)b_s + row * 128 + cb * 16);
      }
#pragma unroll
      for (int tm = 0; tm < 4; ++tm)
#pragma unroll
        for (int tn = 0; tn < 4; ++tn)
          acc[tm][tn] = __builtin_amdgcn_mfma_f32_16x16x32_bf16(af[tm], bfr[tn], acc[tm][tn], 0, 0, 0);
    }
    __syncthreads();
  }
  float bv[4];
#pragma unroll
  for (int tn = 0; tn < 4; ++tn) bv[tn] = bias[n0 + wn * 64 + tn * 16 + l15];
#pragma unroll
  for (int tm = 0; tm < 4; ++tm) {
#pragma unroll
    for (int tp = 0; tp < 2; ++tp) {
#pragma unroll
      for (int r = 0; r < 4; ++r) {
        int t = m0 + wm * 64 + tm * 16 + q * 4 + r;
        __bf16 lo = (__bf16)(acc[tm][tp * 2][r] + bv[tp * 2]);
        __bf16 hi = (__bf16)(acc[tm][tp * 2 + 1][r] + bv[tp * 2 + 1]);
        unsigned short ulo, uhi;
        __builtin_memcpy(&ulo, &lo, 2); __builtin_memcpy(&uhi, &hi, 2);
        uint32_t u = (uint32_t)ulo | ((uint32_t)uhi << 16);
        *(uint32_t*)(g_ig + (size_t)t * ROWB + ntb * 256 + (wn * 2 + tp) * 64 + l15 * 4) = u;
      }
    }
  }
}

// phase 2: the scan.
//  - z/n-gate W_hh in AGPRs, consumed directly by "a"-class asm MFMA;
//    r-gate in per-wave LDS. First MFMA of each chain uses srcC=0 inline
//    constant (no init movs, no init hazard). MFMA->VALU hazard guarded by a
//    dependency-carrying s_nop asm (in/outs on the accs -> cannot be displaced).
//  - igates: direct per-thread global loads, register double-buffered.
//  - h_s double-buffered -> one raw barrier/iter (lgkmcnt only; vmcnt in flight).
__global__ __launch_bounds__(512)
__attribute__((amdgpu_waves_per_eu(2, 2)))
void gru_scan(const float* __restrict__ state, const int* __restrict__ start,
              const float* __restrict__ bias_n, float* __restrict__ out) {
  __shared__ __align__(16) __bf16 h_s[2][16][264];
  __shared__ __align__(16) unsigned char whh_lds[8 * 16 * 1024];
  __shared__ int flg_s[16 * 132];
  __shared__ int s_arr[17];

  const int tid = threadIdx.x;
  const int w = tid >> 6, lane = tid & 63, l15 = lane & 15, q = lane >> 4;
  const int jrow0 = w * 32 + l15;

  if (tid < 17) {
    int t = (blockIdx.x * NCH + tid) * CNOM;
    if (t > 0) { while (t < TT && start[t] == 0) t++; }
    s_arr[tid] = t;
  }
  for (int i = tid; i < 16 * 264; i += 512) (&h_s[0][0][0])[i] = (__bf16)0.f;
  __syncthreads();

  int sa[4], len[4];
#pragma unroll
  for (int r = 0; r < 4; ++r) {
    sa[r] = s_arr[q * 4 + r];
    len[r] = s_arr[q * 4 + r + 1] - sa[r];
  }
  int ML = 0;
  for (int m = 0; m < 16; ++m) { int L = s_arr[m + 1] - s_arr[m]; ML = L > ML ? L : ML; }
  ML = __builtin_amdgcn_readfirstlane(ML);

  // start-flag table: flg_s[m][kk] = start[s_arr[m]+kk] for kk<128
  for (int idx = tid; idx < 2048; idx += 512) {
    int m = idx >> 7, kk = idx & 127;
    int t = s_arr[m] + kk;
    flg_s[m * 132 + kk] = (t < TT) ? start[t] : 0;
  }

  // W_hh c=0 (r-gate) -> per-wave LDS
  char* lp = (char*)whh_lds + w * 16384 + lane * 16;
#pragma unroll
  for (int p = 0; p < 2; ++p)
#pragma unroll
    for (int ks = 0; ks < 8; ++ks) {
      i32x4 t = *(const i32x4*)&g_whh[(size_t)(w * 32 + p * 16 + l15) * 256 + q * 8 + ks * 32];
      *(i32x4*)(lp + (p * 8 + ks) * 1024) = t;
    }
  // W_hh c=1 (z) and c=2 (n) -> AGPRs, pinned; all uses are "a"-class asm MFMA.
  i32x4 whh_z[2][8], whh_n[2][8];
#pragma unroll
  for (int p = 0; p < 2; ++p)
#pragma unroll
    for (int ks = 0; ks < 8; ++ks) {
      whh_z[p][ks] = *(const i32x4*)&g_whh[(size_t)(1 * 256 + w * 32 + p * 16 + l15) * 256 + q * 8 + ks * 32];
      whh_n[p][ks] = *(const i32x4*)&g_whh[(size_t)(2 * 256 + w * 32 + p * 16 + l15) * 256 + q * 8 + ks * 32];
    }
#pragma unroll
  for (int p = 0; p < 2; ++p)
#pragma unroll
    for (int ks = 0; ks < 8; ++ks) {
      asm volatile("" : "+a"(whh_z[p][ks]));
      asm volatile("" : "+a"(whh_n[p][ks]));
    }

  const float bn2[2] = { bias_n[jrow0], bias_n[jrow0 + 16] };

  const int start0 = start[0];
  if (blockIdx.x == 0 && tid < 256) h_s[0][0][tid] = start0 ? (__bf16)0.f : (__bf16)state[tid];

  float hreg[2][4];
#pragma unroll
  for (int p = 0; p < 2; ++p)
#pragma unroll
    for (int r = 0; r < 4; ++r) hreg[p][r] = 0.f;
  if (blockIdx.x == 0 && q == 0 && !start0) {
    hreg[0][0] = state[jrow0];
    hreg[1][0] = state[jrow0 + 16];
  }

  // igate direct-load geometry
  const int cw = (w >> 2) * 256 + ((w & 3) * 16 + l15) * 4;
  const uint32_t offlim = (uint32_t)(TT - 1) * ROWB + (uint32_t)cw;
  uint32_t off[4];
  float* op[4];
#pragma unroll
  for (int r = 0; r < 4; ++r) {
    off[r] = (uint32_t)sa[r] * ROWB + (uint32_t)cw;
    op[r] = out + (size_t)sa[r] * 256 + jrow0;
  }

  const unsigned char* gig = g_ig;
  uint32_t igA[12], igB[12];
#pragma unroll
  for (int r = 0; r < 4; ++r) {
    igA[r * 3 + 0] = *(const uint32_t*)(gig + off[r]);
    igA[r * 3 + 1] = *(const uint32_t*)(gig + off[r] + 512);
    igA[r * 3 + 2] = *(const uint32_t*)(gig + off[r] + 1024);
    uint32_t nx = off[r] + ROWB; off[r] = nx > offlim ? offlim : nx;
  }
  __syncthreads();

  auto step = [&](int k, uint32_t (&cur)[12], uint32_t (&nxt)[12]) {
    // prefetch igates(k+1) -> regs (latency hidden under MFMA + next barrier)
#pragma unroll
    for (int r = 0; r < 4; ++r) {
      nxt[r * 3 + 0] = *(const uint32_t*)(gig + off[r]);
      nxt[r * 3 + 1] = *(const uint32_t*)(gig + off[r] + 512);
      nxt[r * 3 + 2] = *(const uint32_t*)(gig + off[r] + 1024);
      uint32_t nx = off[r] + ROWB; off[r] = nx > offlim ? offlim : nx;
    }
    int fnext[4];
    if (k + 1 < 128) {
#pragma unroll
      for (int r = 0; r < 4; ++r) fnext[r] = flg_s[(q * 4 + r) * 132 + k + 1];
    } else {
#pragma unroll
      for (int r = 0; r < 4; ++r) {
        int t = sa[r] + k + 1; t = t > TT - 1 ? TT - 1 : t;
        fnext[r] = start[t];
      }
    }

    const __bf16* hb = &h_s[k & 1][0][0] + l15 * 264 + q * 8;
#pragma unroll
    for (int p = 0; p < 2; ++p) {
      f32x4 a0, a1, a2;
      {
        bf16x8 hf = *(const bf16x8*)(hb);
        i32x4 b0 = *(const i32x4*)(lp + (p * 8) * 1024);
        mfma_bv0(a0, hf, b0);
        mfma_ba0(a1, hf, whh_z[p][0]);
        mfma_ba0(a2, hf, whh_n[p][0]);
      }
#pragma unroll
      for (int ks = 1; ks < 8; ++ks) {
        bf16x8 hf = *(const bf16x8*)(hb + ks * 32);
        i32x4 b0 = *(const i32x4*)(lp + (p * 8 + ks) * 1024);
        mfma_bv(a0, hf, b0);
        mfma_ba(a1, hf, whh_z[p][ks]);
        mfma_ba(a2, hf, whh_n[p][ks]);
      }
      // MFMA dst -> VALU read hazard guard; in/outs on accs pin its position.
      asm volatile("s_nop 7\n\ts_nop 7" : "+v"(a0), "+v"(a1), "+v"(a2));
#pragma unroll
      for (int r = 0; r < 4; ++r) {
        uint32_t vr = cur[r * 3 + 0];
        uint32_t vz = cur[r * 3 + 1];
        uint32_t vn = cur[r * 3 + 2];
        float igr = bfbits(p ? (vr & 0xffff0000u) : (vr << 16));
        float igz = bfbits(p ? (vz & 0xffff0000u) : (vz << 16));
        float ign = bfbits(p ? (vn & 0xffff0000u) : (vn << 16));
        float rp_ = a0[r] + igr;
        float zp_ = a1[r] + igz;
        float hv  = a2[r] + bn2[p];
        float rg = 1.f / (1.f + __expf(-rp_));
        float zg = 1.f / (1.f + __expf(-zp_));
        float np = ign + rg * hv;
        np = fminf(fmaxf(np, -30.f), 30.f);
        float e2 = __expf(2.f * np);
        float ng = (e2 - 1.f) / (e2 + 1.f);
        float hn = ng + zg * (hreg[p][r] - ng);
        if (k < len[r]) op[r][p * 16] = hn;
        hreg[p][r] = fnext[r] ? 0.f : hn;
      }
    }
    __bf16* hw = &h_s[(k + 1) & 1][0][0];
#pragma unroll
    for (int p = 0; p < 2; ++p)
#pragma unroll
      for (int r = 0; r < 4; ++r)
        hw[(q * 4 + r) * 264 + jrow0 + p * 16] = (__bf16)hreg[p][r];
#pragma unroll
    for (int r = 0; r < 4; ++r) op[r] += 256;
    // one raw barrier per step: drain LDS only; vmcnt stays in flight
    asm volatile("s_waitcnt lgkmcnt(0)" ::: "memory");
    __builtin_amdgcn_s_barrier();
  };

  for (int k = 0; k < ML; ) {
    step(k, igA, igB); ++k;
    if (k < ML) { step(k, igB, igA); ++k; }
  }
}

__global__ void fin_copy(float* __restrict__ out) {
  int i = threadIdx.x;
  out[(size_t)TT * 256 + i] = out[((size_t)TT - 1) * 256 + i];
}

extern "C" void kernel_launch(void* const* d_in, const int* in_sizes, int n_in,
                              void* d_out, int out_size, void* d_ws, size_t ws_size,
                              hipStream_t stream) {
  const float* x      = (const float*)d_in[0];
  const float* state  = (const float*)d_in[1];
  const int*   start  = (const int*)d_in[2];
  const float* wih    = (const float*)d_in[4];
  const float* whh    = (const float*)d_in[5];
  const float* bias   = (const float*)d_in[6];
  const float* bias_n = (const float*)d_in[7];
  float* out = (float*)d_out;

  prep_w<<<256, 256, 0, stream>>>(wih, whh);
  gemm_ig<<<3072, 256, 0, stream>>>(x, bias);
  gru_scan<<<NBLK, 512, 0, stream>>>(state, start, bias_n, out);
  fin_copy<<<1, 256, 0, stream>>>(out);
}

// Round 6
// 281.822 us; speedup vs baseline: 1.0786x; 1.0786x over previous
//
#include <hip/hip_runtime.h>
#include <hip/hip_bf16.h>
#include <stdint.h>

#define TT   65536
#define NCH  16
#define CNOM 16
#define NBLK 256
#define ROWB 1664            // bytes per packed igate row (6*256 used + 128 pad)

typedef __bf16 bf16x8 __attribute__((ext_vector_type(8)));
typedef float  f32x4  __attribute__((ext_vector_type(4)));
typedef int    i32x4  __attribute__((ext_vector_type(4)));

__device__ __bf16 g_whh[768 * 256];
__device__ __align__(64) unsigned char g_ig[(size_t)TT * ROWB];

__device__ __forceinline__ float bfbits(uint32_t u) {
  float f; __builtin_memcpy(&f, &u, 4); return f;
}

// asm MFMA wrappers (scan only). *_0: inline-constant-0 srcC, "=&v" early-clobber.
__device__ __forceinline__ void mfma_bv0(f32x4& acc, bf16x8 a, i32x4 b) {
  asm("v_mfma_f32_16x16x32_bf16 %0, %1, %2, 0" : "=&v"(acc) : "v"(a), "v"(b));
}
__device__ __forceinline__ void mfma_ba0(f32x4& acc, bf16x8 a, i32x4 b) {
  asm("v_mfma_f32_16x16x32_bf16 %0, %1, %2, 0" : "=&v"(acc) : "v"(a), "a"(b));
}
__device__ __forceinline__ void mfma_bv(f32x4& acc, bf16x8 a, i32x4 b) {
  asm("v_mfma_f32_16x16x32_bf16 %0, %1, %2, %0" : "+v"(acc) : "v"(a), "v"(b));
}
__device__ __forceinline__ void mfma_ba(f32x4& acc, bf16x8 a, i32x4 b) {
  asm("v_mfma_f32_16x16x32_bf16 %0, %1, %2, %0" : "+v"(acc) : "v"(a), "a"(b));
}

__device__ __forceinline__ bf16x8 cvt8(float4 f0, float4 f1) {
  bf16x8 v;
  v[0] = (__bf16)f0.x; v[1] = (__bf16)f0.y; v[2] = (__bf16)f0.z; v[3] = (__bf16)f0.w;
  v[4] = (__bf16)f1.x; v[5] = (__bf16)f1.y; v[6] = (__bf16)f1.z; v[7] = (__bf16)f1.w;
  return v;
}

__global__ void prep_w(const float* __restrict__ whh) {
  const int n = 768 * 256;
  for (int i = blockIdx.x * blockDim.x + threadIdx.x; i < n; i += gridDim.x * blockDim.x)
    g_whh[i] = (__bf16)whh[i];
}

// phase 1: igates = x @ W_ih^T + bias -> packed rows.
// ONE block per 128-row m-tile (grid 512). x staged ONCE into 64 KB LDS
// (4 kc-chunks, write-side swizzle, f32->bf16 inline); the 6 n-tiles loop
// INSIDE the block with a 2x16KB double-buffered W panel, reg-staged from f32
// wih (issue-early/write-late). Kills the 3x x over-fetch (201 MB FETCH)
// caused by 6 same-mt blocks landing on 6 different XCD L2s.
__global__ __launch_bounds__(512) void gemm_ig(const float* __restrict__ x,
                                               const float* __restrict__ wih,
                                               const float* __restrict__ bias) {
  __shared__ __align__(16) __bf16 a_s[4][128 * 64];   // 64 KB: x tile, kc-chunked
  __shared__ __align__(16) __bf16 b_s[2][128 * 64];   // 32 KB: W panel dbuf
  const int tid = threadIdx.x;
  const int lane = tid & 63, l15 = lane & 15, q = lane >> 4;
  const int w = tid >> 6;
  const int wm = w >> 2, wn = w & 3;                  // 2 x 4 wave grid
  const int m0 = blockIdx.x * 128;

  float bvA[6], bvB[6];
#pragma unroll
  for (int nb = 0; nb < 6; ++nb) {
    bvA[nb] = bias[nb * 128 + wn * 32 + l15];
    bvB[nb] = bias[nb * 128 + wn * 32 + 16 + l15];
  }

  // stage x once: LDS[row][c] = global chunk c^(row&7) (write-side swizzle;
  // read side uses cb=(ks*4+q)^(row&7) -> retrieves linear chunk ks*4+q).
#pragma unroll
  for (int kc = 0; kc < 4; ++kc)
#pragma unroll
    for (int i = 0; i < 2; ++i) {
      int pslot = i * 512 + tid;
      int row = pslot >> 3, c = pslot & 7, cs = c ^ (row & 7);
      const float* xs = x + (size_t)(m0 + row) * 256 + kc * 64 + cs * 8;
      float4 f0 = *(const float4*)xs;
      float4 f1 = *(const float4*)(xs + 4);
      *(bf16x8*)((char*)a_s[kc] + pslot * 16) = cvt8(f0, f1);
    }
  // prologue: W(ntb=0,kc=0) -> b_s[0]
#pragma unroll
  for (int i = 0; i < 2; ++i) {
    int pslot = i * 512 + tid;
    int row = pslot >> 3, c = pslot & 7, cs = c ^ (row & 7);
    const float* ws = wih + (size_t)(row) * 256 + cs * 8;
    float4 f0 = *(const float4*)ws;
    float4 f1 = *(const float4*)(ws + 4);
    *(bf16x8*)((char*)b_s[0] + pslot * 16) = cvt8(f0, f1);
  }

  f32x4 acc[4][2];
#pragma unroll
  for (int a = 0; a < 4; ++a)
#pragma unroll
    for (int b = 0; b < 2; ++b) acc[a][b] = (f32x4){0.f, 0.f, 0.f, 0.f};
  __syncthreads();

#pragma unroll
  for (int ntb = 0; ntb < 6; ++ntb) {
#pragma unroll
    for (int kc = 0; kc < 4; ++kc) {
      const int ci = ntb * 4 + kc;
      const int buf = ci & 1;
      const int nn = (ci + 1) >> 2, kk = (ci + 1) & 3;
      const bool more = (ci + 1) < 24;
      float4 wf00, wf01, wf10, wf11;
      if (more) {   // issue next W panel loads early (hidden under MFMA)
        int ps0 = tid, r0 = ps0 >> 3, cs0 = (ps0 & 7) ^ (r0 & 7);
        const float* ws0 = wih + (size_t)(nn * 128 + r0) * 256 + kk * 64 + cs0 * 8;
        wf00 = *(const float4*)ws0; wf01 = *(const float4*)(ws0 + 4);
        int ps1 = 512 + tid, r1 = ps1 >> 3, cs1 = (ps1 & 7) ^ (r1 & 7);
        const float* ws1 = wih + (size_t)(nn * 128 + r1) * 256 + kk * 64 + cs1 * 8;
        wf10 = *(const float4*)ws1; wf11 = *(const float4*)(ws1 + 4);
      }
#pragma unroll
      for (int ks = 0; ks < 2; ++ks) {
        bf16x8 af[4], bfr[2];
#pragma unroll
        for (int tm = 0; tm < 4; ++tm) {
          int row = wm * 64 + tm * 16 + l15;
          int cb = (ks * 4 + q) ^ (row & 7);
          af[tm] = *(const bf16x8*)((const char*)a_s[kc] + row * 128 + cb * 16);
        }
#pragma unroll
        for (int tn = 0; tn < 2; ++tn) {
          int row = wn * 32 + tn * 16 + l15;
          int cb = (ks * 4 + q) ^ (row & 7);
          bfr[tn] = *(const bf16x8*)((const char*)b_s[buf] + row * 128 + cb * 16);
        }
#pragma unroll
        for (int tm = 0; tm < 4; ++tm)
#pragma unroll
          for (int tn = 0; tn < 2; ++tn)
            acc[tm][tn] = __builtin_amdgcn_mfma_f32_16x16x32_bf16(af[tm], bfr[tn], acc[tm][tn], 0, 0, 0);
      }
      if (more) {   // write next W panel into the idle buffer (read next iter)
        *(bf16x8*)((char*)b_s[buf ^ 1] + tid * 16) = cvt8(wf00, wf01);
        *(bf16x8*)((char*)b_s[buf ^ 1] + (512 + tid) * 16) = cvt8(wf10, wf11);
      }
      if (kc == 3) {
#pragma unroll
        for (int tm = 0; tm < 4; ++tm)
#pragma unroll
          for (int r = 0; r < 4; ++r) {
            int t = m0 + wm * 64 + tm * 16 + q * 4 + r;
            __bf16 lo = (__bf16)(acc[tm][0][r] + bvA[ntb]);
            __bf16 hi = (__bf16)(acc[tm][1][r] + bvB[ntb]);
            unsigned short ulo, uhi;
            __builtin_memcpy(&ulo, &lo, 2); __builtin_memcpy(&uhi, &hi, 2);
            uint32_t u = (uint32_t)ulo | ((uint32_t)uhi << 16);
            *(uint32_t*)(g_ig + (size_t)t * ROWB + ntb * 256 + wn * 64 + l15 * 4) = u;
          }
#pragma unroll
        for (int a = 0; a < 4; ++a)
#pragma unroll
          for (int b = 0; b < 2; ++b) acc[a][b] = (f32x4){0.f, 0.f, 0.f, 0.f};
      }
      __syncthreads();
    }
  }
}

// phase 2: the scan — unchanged from R4 (passing). z/n-gate W_hh in AGPRs via
// "a"-class asm MFMA; r-gate in per-wave LDS; igates reg-double-buffered
// direct loads; one raw barrier per step.
__global__ __launch_bounds__(512)
__attribute__((amdgpu_waves_per_eu(2, 2)))
void gru_scan(const float* __restrict__ state, const int* __restrict__ start,
              const float* __restrict__ bias_n, float* __restrict__ out) {
  __shared__ __align__(16) __bf16 h_s[2][16][264];
  __shared__ __align__(16) unsigned char whh_lds[8 * 16 * 1024];
  __shared__ int flg_s[16 * 132];
  __shared__ int s_arr[17];

  const int tid = threadIdx.x;
  const int w = tid >> 6, lane = tid & 63, l15 = lane & 15, q = lane >> 4;
  const int jrow0 = w * 32 + l15;

  if (tid < 17) {
    int t = (blockIdx.x * NCH + tid) * CNOM;
    if (t > 0) { while (t < TT && start[t] == 0) t++; }
    s_arr[tid] = t;
  }
  for (int i = tid; i < 16 * 264; i += 512) (&h_s[0][0][0])[i] = (__bf16)0.f;
  __syncthreads();

  int sa[4], len[4];
#pragma unroll
  for (int r = 0; r < 4; ++r) {
    sa[r] = s_arr[q * 4 + r];
    len[r] = s_arr[q * 4 + r + 1] - sa[r];
  }
  int ML = 0;
  for (int m = 0; m < 16; ++m) { int L = s_arr[m + 1] - s_arr[m]; ML = L > ML ? L : ML; }
  ML = __builtin_amdgcn_readfirstlane(ML);

  for (int idx = tid; idx < 2048; idx += 512) {
    int m = idx >> 7, kk = idx & 127;
    int t = s_arr[m] + kk;
    flg_s[m * 132 + kk] = (t < TT) ? start[t] : 0;
  }

  // W_hh c=0 (r-gate) -> per-wave LDS
  char* lp = (char*)whh_lds + w * 16384 + lane * 16;
#pragma unroll
  for (int p = 0; p < 2; ++p)
#pragma unroll
    for (int ks = 0; ks < 8; ++ks) {
      i32x4 t = *(const i32x4*)&g_whh[(size_t)(w * 32 + p * 16 + l15) * 256 + q * 8 + ks * 32];
      *(i32x4*)(lp + (p * 8 + ks) * 1024) = t;
    }
  // W_hh c=1 (z), c=2 (n) -> AGPRs
  i32x4 whh_z[2][8], whh_n[2][8];
#pragma unroll
  for (int p = 0; p < 2; ++p)
#pragma unroll
    for (int ks = 0; ks < 8; ++ks) {
      whh_z[p][ks] = *(const i32x4*)&g_whh[(size_t)(1 * 256 + w * 32 + p * 16 + l15) * 256 + q * 8 + ks * 32];
      whh_n[p][ks] = *(const i32x4*)&g_whh[(size_t)(2 * 256 + w * 32 + p * 16 + l15) * 256 + q * 8 + ks * 32];
    }
#pragma unroll
  for (int p = 0; p < 2; ++p)
#pragma unroll
    for (int ks = 0; ks < 8; ++ks) {
      asm volatile("" : "+a"(whh_z[p][ks]));
      asm volatile("" : "+a"(whh_n[p][ks]));
    }

  const float bn2[2] = { bias_n[jrow0], bias_n[jrow0 + 16] };

  const int start0 = start[0];
  if (blockIdx.x == 0 && tid < 256) h_s[0][0][tid] = start0 ? (__bf16)0.f : (__bf16)state[tid];

  float hreg[2][4];
#pragma unroll
  for (int p = 0; p < 2; ++p)
#pragma unroll
    for (int r = 0; r < 4; ++r) hreg[p][r] = 0.f;
  if (blockIdx.x == 0 && q == 0 && !start0) {
    hreg[0][0] = state[jrow0];
    hreg[1][0] = state[jrow0 + 16];
  }

  const int cw = (w >> 2) * 256 + ((w & 3) * 16 + l15) * 4;
  const uint32_t offlim = (uint32_t)(TT - 1) * ROWB + (uint32_t)cw;
  uint32_t off[4];
  float* op[4];
#pragma unroll
  for (int r = 0; r < 4; ++r) {
    off[r] = (uint32_t)sa[r] * ROWB + (uint32_t)cw;
    op[r] = out + (size_t)sa[r] * 256 + jrow0;
  }

  const unsigned char* gig = g_ig;
  uint32_t igA[12], igB[12];
#pragma unroll
  for (int r = 0; r < 4; ++r) {
    igA[r * 3 + 0] = *(const uint32_t*)(gig + off[r]);
    igA[r * 3 + 1] = *(const uint32_t*)(gig + off[r] + 512);
    igA[r * 3 + 2] = *(const uint32_t*)(gig + off[r] + 1024);
    uint32_t nx = off[r] + ROWB; off[r] = nx > offlim ? offlim : nx;
  }
  __syncthreads();

  auto step = [&](int k, uint32_t (&cur)[12], uint32_t (&nxt)[12]) {
#pragma unroll
    for (int r = 0; r < 4; ++r) {
      nxt[r * 3 + 0] = *(const uint32_t*)(gig + off[r]);
      nxt[r * 3 + 1] = *(const uint32_t*)(gig + off[r] + 512);
      nxt[r * 3 + 2] = *(const uint32_t*)(gig + off[r] + 1024);
      uint32_t nx = off[r] + ROWB; off[r] = nx > offlim ? offlim : nx;
    }
    int fnext[4];
    if (k + 1 < 128) {
#pragma unroll
      for (int r = 0; r < 4; ++r) fnext[r] = flg_s[(q * 4 + r) * 132 + k + 1];
    } else {
#pragma unroll
      for (int r = 0; r < 4; ++r) {
        int t = sa[r] + k + 1; t = t > TT - 1 ? TT - 1 : t;
        fnext[r] = start[t];
      }
    }

    const __bf16* hb = &h_s[k & 1][0][0] + l15 * 264 + q * 8;
#pragma unroll
    for (int p = 0; p < 2; ++p) {
      f32x4 a0, a1, a2;
      {
        bf16x8 hf = *(const bf16x8*)(hb);
        i32x4 b0 = *(const i32x4*)(lp + (p * 8) * 1024);
        mfma_bv0(a0, hf, b0);
        mfma_ba0(a1, hf, whh_z[p][0]);
        mfma_ba0(a2, hf, whh_n[p][0]);
      }
#pragma unroll
      for (int ks = 1; ks < 8; ++ks) {
        bf16x8 hf = *(const bf16x8*)(hb + ks * 32);
        i32x4 b0 = *(const i32x4*)(lp + (p * 8 + ks) * 1024);
        mfma_bv(a0, hf, b0);
        mfma_ba(a1, hf, whh_z[p][ks]);
        mfma_ba(a2, hf, whh_n[p][ks]);
      }
      asm volatile("s_nop 7\n\ts_nop 7" : "+v"(a0), "+v"(a1), "+v"(a2));
#pragma unroll
      for (int r = 0; r < 4; ++r) {
        uint32_t vr = cur[r * 3 + 0];
        uint32_t vz = cur[r * 3 + 1];
        uint32_t vn = cur[r * 3 + 2];
        float igr = bfbits(p ? (vr & 0xffff0000u) : (vr << 16));
        float igz = bfbits(p ? (vz & 0xffff0000u) : (vz << 16));
        float ign = bfbits(p ? (vn & 0xffff0000u) : (vn << 16));
        float rp_ = a0[r] + igr;
        float zp_ = a1[r] + igz;
        float hv  = a2[r] + bn2[p];
        float rg = 1.f / (1.f + __expf(-rp_));
        float zg = 1.f / (1.f + __expf(-zp_));
        float np = ign + rg * hv;
        np = fminf(fmaxf(np, -30.f), 30.f);
        float e2 = __expf(2.f * np);
        float ng = (e2 - 1.f) / (e2 + 1.f);
        float hn = ng + zg * (hreg[p][r] - ng);
        if (k < len[r]) op[r][p * 16] = hn;
        hreg[p][r] = fnext[r] ? 0.f : hn;
      }
    }
    __bf16* hw = &h_s[(k + 1) & 1][0][0];
#pragma unroll
    for (int p = 0; p < 2; ++p)
#pragma unroll
      for (int r = 0; r < 4; ++r)
        hw[(q * 4 + r) * 264 + jrow0 + p * 16] = (__bf16)hreg[p][r];
#pragma unroll
    for (int r = 0; r < 4; ++r) op[r] += 256;
    asm volatile("s_waitcnt lgkmcnt(0)" ::: "memory");
    __builtin_amdgcn_s_barrier();
  };

  for (int k = 0; k < ML; ) {
    step(k, igA, igB); ++k;
    if (k < ML) { step(k, igB, igA); ++k; }
  }
}

__global__ void fin_copy(float* __restrict__ out) {
  int i = threadIdx.x;
  out[(size_t)TT * 256 + i] = out[((size_t)TT - 1) * 256 + i];
}

extern "C" void kernel_launch(void* const* d_in, const int* in_sizes, int n_in,
                              void* d_out, int out_size, void* d_ws, size_t ws_size,
                              hipStream_t stream) {
  const float* x      = (const float*)d_in[0];
  const float* state  = (const float*)d_in[1];
  const int*   start  = (const int*)d_in[2];
  const float* wih    = (const float*)d_in[4];
  const float* whh    = (const float*)d_in[5];
  const float* bias   = (const float*)d_in[6];
  const float* bias_n = (const float*)d_in[7];
  float* out = (float*)d_out;

  prep_w<<<256, 256, 0, stream>>>(whh);
  gemm_ig<<<512, 512, 0, stream>>>(x, wih, bias);
  gru_scan<<<NBLK, 512, 0, stream>>>(state, start, bias_n, out);
  fin_copy<<<1, 256, 0, stream>>>(out);
}